// Round 8
// baseline (56.692 us; speedup 1.0000x reference)
//
#include <hip/hip_runtime.h>
#include <math.h>

constexpr int B_   = 8;
constexpr int N_   = 2048;
constexpr int D_   = 32;
constexpr int PIN  = 8;
constexpr int POUT = 4;
constexpr int COLS = 128;      // D_*POUT
constexpr int BM   = 64;       // GEMM row tile
constexpr int BK   = 64;       // GEMM k tile
constexpr int NT   = N_ / BK;  // 32 k-steps

using f32x4  = __attribute__((ext_vector_type(4))) float;
using bf16x8 = __attribute__((ext_vector_type(8))) short;

__device__ __forceinline__ unsigned short f2bf(float f) {
    union { float f; unsigned u; } v; v.f = f;
    unsigned u = v.u + 0x7fffu + ((v.u >> 16) & 1u);   // RTNE
    return (unsigned short)(u >> 16);
}

// 16B global->LDS DMA. LDS dest is wave-uniform base + lane*16 (m104/m108).
__device__ __forceinline__ void dma16(const void* g, void* l) {
    __builtin_amdgcn_global_load_lds(
        (const __attribute__((address_space(1))) unsigned int*)g,
        (__attribute__((address_space(3))) unsigned int*)(uintptr_t)l,
        16, 0, 0);
}

// ---- kernel T: Btg[b][col=4d+o][n] = bf16(U@Wn); Mself[b][n][4d+o] = U@Ws ----
__global__ __launch_bounds__(256) void mneigh_t_kernel(
    const float* __restrict__ U, const float* __restrict__ Wn,
    const float* __restrict__ Ws, unsigned short* __restrict__ Btg,
    float* __restrict__ Mself)
{
    const int bt = blockIdx.x;       // 512 blocks
    const int b  = bt >> 6;          // batch
    const int n0 = (bt & 63) * 32;   // 32 n-rows per block
    const int t  = threadIdx.x;
    const int d  = t >> 3;           // 0..31
    const int ns = t & 7;            // 0..7 -> rows n0+ns*4 .. +3

    float wn[PIN][POUT], ws[PIN][POUT];
#pragma unroll
    for (int p = 0; p < PIN; ++p)
#pragma unroll
        for (int o = 0; o < POUT; ++o) {
            wn[p][o] = Wn[p * POUT + o];
            ws[p][o] = Ws[p * POUT + o];
        }

    union { unsigned short s[4]; int2 v; } ob[POUT];
    const float* Ub = U + (((size_t)(b * N_ + n0 + ns * 4)) * D_ + d) * PIN;
#pragma unroll
    for (int ni = 0; ni < 4; ++ni) {
        const float4 u0 = *(const float4*)(Ub + (size_t)ni * D_ * PIN);
        const float4 u1 = *(const float4*)(Ub + (size_t)ni * D_ * PIN + 4);
        const float uu[8] = {u0.x, u0.y, u0.z, u0.w, u1.x, u1.y, u1.z, u1.w};
        float4 ms;
#pragma unroll
        for (int o = 0; o < POUT; ++o) {
            float sn = 0.f, ss = 0.f;
#pragma unroll
            for (int p = 0; p < PIN; ++p) {
                sn = fmaf(uu[p], wn[p][o], sn);
                ss = fmaf(uu[p], ws[p][o], ss);
            }
            ob[o].s[ni] = f2bf(sn);
            ((float*)&ms)[o] = ss;
        }
        *(float4*)(Mself + ((size_t)(b * N_ + n0 + ns * 4 + ni)) * COLS + d * 4) = ms;
    }
#pragma unroll
    for (int o = 0; o < POUT; ++o) {
        unsigned short* dst =
            Btg + ((size_t)(b * COLS + d * 4 + o)) * N_ + n0 + ns * 4;
        *(int2*)dst = ob[o].v;
    }
}

// ---- kernel G: M_agg = A @ Mneigh (bf16 MFMA); Y=relu(+Mself+bias); polar ----
// Triple-buffered DMA staging (depth-3 prefetch: slack ~2 iterations > HBM
// latency), counted vmcnt (8/4/0), raw barriers, 1 block/CU.
__global__ __launch_bounds__(512, 1) void gemm_proj_kernel(
    const float* __restrict__ A, const unsigned short* __restrict__ Btg,
    const float* __restrict__ Mself, const float* __restrict__ bias,
    float* __restrict__ out)
{
    __shared__ unsigned char smem[98304];
    // A f32 [3][64r][64k] @0 (3x16KB, 16-row 16B-slot XOR swizzle)
    // B bf16 [3][128c][64k] @49152 (3x16KB, 8-row XOR swizzle)
    // epilogue reuse @0: Yl f32 [64][132] (33792); Gp @33792; Sm @44032
    float* Yl = (float*)smem;
    float* Gp = (float*)(smem + 33792);
    float* Sm = (float*)(smem + 44032);

    // T1: bijective XCD swizzle (256 % 8 == 0): XCD x owns batch x.
    const int bid = (blockIdx.x & 7) * 32 + (blockIdx.x >> 3);
    const int b   = bid >> 5;
    const int r0  = (bid & 31) * BM;
    const int t   = threadIdx.x;
    const int lane = t & 63, wv = t >> 6;
    const int wr = wv >> 1, wc = wv & 1;       // wave -> 16 rows x 64 cols
    const int q = lane >> 4, rl = lane & 15;
    const int rA = wr * 16 + rl;
    const unsigned arx = (unsigned)((rA & 15) << 4);

    const char* Ab = (const char*)(A + (size_t)b * N_ * N_ + (size_t)r0 * N_);
    const char* Bb = (const char*)(Btg + (size_t)b * COLS * N_);

    // DMA source addresses (pre-swizzled; LDS dest linear per lane)
    const int arow = wv * 4 + (lane >> 4);              // 0..31 (round0)
    const unsigned ain = ((unsigned)((lane & 15) * 16)) ^
                         ((unsigned)((arow & 15) << 4));
    const char* a_src0 = Ab + (size_t)arow * 8192 + ain;
    const char* a_src1 = a_src0 + (size_t)32 * 8192;    // row+32, same swz
    const int bcol = wv * 8 + (lane >> 3);              // 0..63 (round0)
    const unsigned bin = ((unsigned)((lane & 7) * 16)) ^
                         ((unsigned)((bcol & 7) << 4));
    const char* b_src0 = Bb + (size_t)bcol * 4096 + bin;
    const char* b_src1 = b_src0 + (size_t)64 * 4096;    // col+64, same swz

#define STAGE(K0, BUF)                                                \
    do {                                                              \
        unsigned char* ad = smem + (BUF) * 16384 + wv * 1024;         \
        unsigned char* bd = smem + 49152 + (BUF) * 16384 + wv * 1024; \
        dma16(a_src0 + (size_t)(K0) * 4, ad);                         \
        dma16(a_src1 + (size_t)(K0) * 4, ad + 8192);                  \
        dma16(b_src0 + (size_t)(K0) * 2, bd);                         \
        dma16(b_src1 + (size_t)(K0) * 2, bd + 8192);                  \
    } while (0)

    f32x4 acc[4] = {f32x4{0,0,0,0}, f32x4{0,0,0,0},
                    f32x4{0,0,0,0}, f32x4{0,0,0,0}};

    STAGE(0, 0);
    STAGE(BK, 1);
    STAGE(2 * BK, 2);

    int bufsel = 0;
    for (int kt = 0; kt < NT; ++kt) {
        // wait until tile kt fully landed (counted: 2/1/0 tiles remain in flight)
        if (kt < NT - 2)       asm volatile("s_waitcnt vmcnt(8)" ::: "memory");
        else if (kt == NT - 2) asm volatile("s_waitcnt vmcnt(4)" ::: "memory");
        else                   asm volatile("s_waitcnt vmcnt(0)" ::: "memory");
        __builtin_amdgcn_s_barrier();   // all waves' portions landed

        const unsigned abase = (unsigned)bufsel * 16384u;
        const unsigned bbase = 49152u + (unsigned)bufsel * 16384u;
        __builtin_amdgcn_s_setprio(1);
#pragma unroll
        for (int ks = 0; ks < 2; ++ks) {
            const unsigned off0 = ((unsigned)(ks * 128 + q * 32)) ^ arx;
            const unsigned off1 = ((unsigned)(ks * 128 + q * 32 + 16)) ^ arx;
            const float4 alo = *(const float4*)(smem + abase + rA * 256 + off0);
            const float4 ahi = *(const float4*)(smem + abase + rA * 256 + off1);
            union { unsigned u[4]; bf16x8 v; } af;
            asm("v_cvt_pk_bf16_f32 %0, %1, %2"
                : "=v"(af.u[0]) : "v"(alo.x), "v"(alo.y));
            asm("v_cvt_pk_bf16_f32 %0, %1, %2"
                : "=v"(af.u[1]) : "v"(alo.z), "v"(alo.w));
            asm("v_cvt_pk_bf16_f32 %0, %1, %2"
                : "=v"(af.u[2]) : "v"(ahi.x), "v"(ahi.y));
            asm("v_cvt_pk_bf16_f32 %0, %1, %2"
                : "=v"(af.u[3]) : "v"(ahi.z), "v"(ahi.w));
#pragma unroll
            for (int cf = 0; cf < 4; ++cf) {
                const int rB = wc * 64 + cf * 16 + rl;
                const bf16x8 bfr = *(const bf16x8*)(
                    smem + bbase + rB * 128 +
                    (((unsigned)(ks * 64 + q * 16)) ^ ((unsigned)((rB & 7) << 4))));
                acc[cf] = __builtin_amdgcn_mfma_f32_16x16x32_bf16(
                    af.v, bfr, acc[cf], 0, 0, 0);
            }
        }
        __builtin_amdgcn_s_setprio(0);
        __builtin_amdgcn_s_barrier();   // all waves done reading buf[bufsel]
        if (kt + 3 < NT) STAGE((kt + 3) * BK, bufsel);
        bufsel = (bufsel == 2) ? 0 : bufsel + 1;
    }
#undef STAGE
    asm volatile("s_waitcnt vmcnt(0)" ::: "memory");
    __syncthreads();   // smem repurposed below

    // ---- epilogue ----
    // 1) M_agg -> Yl   (C/D map: col=lane&15, row=(lane>>4)*4+r  [m89])
#pragma unroll
    for (int cf = 0; cf < 4; ++cf)
#pragma unroll
        for (int r = 0; r < 4; ++r) {
            const int row = wr * 16 + q * 4 + r;
            const int col = wc * 64 + cf * 16 + rl;
            Yl[row * 132 + col] = acc[cf][r];
        }
    __syncthreads();

    // 2) Y = relu(M_agg + M_self + bias)
    const float bz[4] = {bias[0], bias[1], bias[2], bias[3]};
    const float* Mb = Mself + ((size_t)(b * N_ + r0)) * COLS;
#pragma unroll
    for (int i = 0; i < 4; ++i) {
        const int cell = t + i * 512;     // 2048 cells = 64 rows x 32 d
        const int row = cell >> 5, d = cell & 31;
        const float4 m = *(const float4*)(Mb + (size_t)row * COLS + d * 4);
        const int idx = row * 132 + d * 4;
        float4 y = *(const float4*)(Yl + idx);
        y.x = fmaxf(y.x + m.x + bz[0], 0.f);
        y.y = fmaxf(y.y + m.y + bz[1], 0.f);
        y.z = fmaxf(y.z + m.z + bz[2], 0.f);
        y.w = fmaxf(y.w + m.w + bz[3], 0.f);
        *(float4*)(Yl + idx) = y;
    }
    __syncthreads();

    // 3) G partials: 4 threads per row
    if (t < 256) {
        const int row = t >> 2, qd = t & 3;
        float g[10] = {0,0,0,0,0,0,0,0,0,0};
#pragma unroll
        for (int d = qd * 8; d < qd * 8 + 8; ++d) {
            const float4 y = *(const float4*)(Yl + row * 132 + 4 * d);
            g[0] = fmaf(y.x, y.x, g[0]); g[1] = fmaf(y.x, y.y, g[1]);
            g[2] = fmaf(y.x, y.z, g[2]); g[3] = fmaf(y.x, y.w, g[3]);
            g[4] = fmaf(y.y, y.y, g[4]); g[5] = fmaf(y.y, y.z, g[5]);
            g[6] = fmaf(y.y, y.w, g[6]); g[7] = fmaf(y.z, y.z, g[7]);
            g[8] = fmaf(y.z, y.w, g[8]); g[9] = fmaf(y.w, y.w, g[9]);
        }
        float* gp = Gp + (row * 4 + qd) * 10;
#pragma unroll
        for (int k = 0; k < 10; ++k) gp[k] = g[k];
    }
    __syncthreads();

    // 4) Jacobi eigendecomposition + S = V diag(1/sqrt(l)) V^T  (1 thread/row)
    if (t < 64) {
        float gg[10];
#pragma unroll
        for (int k = 0; k < 10; ++k)
            gg[k] = Gp[(t * 4 + 0) * 10 + k] + Gp[(t * 4 + 1) * 10 + k] +
                    Gp[(t * 4 + 2) * 10 + k] + Gp[(t * 4 + 3) * 10 + k];
        float m[4][4] = {{gg[0], gg[1], gg[2], gg[3]},
                         {gg[1], gg[4], gg[5], gg[6]},
                         {gg[2], gg[5], gg[7], gg[8]},
                         {gg[3], gg[6], gg[8], gg[9]}};
        float v[4][4] = {{1,0,0,0},{0,1,0,0},{0,0,1,0},{0,0,0,1}};
        for (int sweep = 0; sweep < 6; ++sweep) {
#pragma unroll
            for (int p = 0; p < 3; ++p) {
#pragma unroll
                for (int qq = p + 1; qq < 4; ++qq) {
                    const float apq = m[p][qq];
                    if (fabsf(apq) < 1e-28f) continue;
                    const float theta = (m[qq][qq] - m[p][p]) / (2.f * apq);
                    const float tt = copysignf(1.f, theta) /
                        (fabsf(theta) + sqrtf(fmaf(theta, theta, 1.f)));
                    const float c = 1.f / sqrtf(fmaf(tt, tt, 1.f));
                    const float s = tt * c;
#pragma unroll
                    for (int k = 0; k < 4; ++k) {
                        const float mkp = m[k][p], mkq = m[k][qq];
                        m[k][p] = c * mkp - s * mkq;
                        m[k][qq] = s * mkp + c * mkq;
                    }
#pragma unroll
                    for (int k = 0; k < 4; ++k) {
                        const float mpk = m[p][k], mqk = m[qq][k];
                        m[p][k] = c * mpk - s * mqk;
                        m[qq][k] = s * mpk + c * mqk;
                    }
#pragma unroll
                    for (int k = 0; k < 4; ++k) {
                        const float vkp = v[k][p], vkq = v[k][qq];
                        v[k][p] = c * vkp - s * vkq;
                        v[k][qq] = s * vkp + c * vkq;
                    }
                }
            }
        }
        const float lam[4] = {m[0][0], m[1][1], m[2][2], m[3][3]};
        const float lmax = fmaxf(fmaxf(lam[0], lam[1]), fmaxf(lam[2], lam[3]));
        const float lfloor = fmaxf(lmax * 1e-12f, 1e-30f);
        float rlv[4];
#pragma unroll
        for (int k = 0; k < 4; ++k) rlv[k] = 1.f / sqrtf(fmaxf(lam[k], lfloor));
#pragma unroll
        for (int i = 0; i < 4; ++i)
#pragma unroll
            for (int j = 0; j < 4; ++j)
                Sm[t * 16 + i * 4 + j] =
                    v[i][0] * v[j][0] * rlv[0] + v[i][1] * v[j][1] * rlv[1] +
                    v[i][2] * v[j][2] * rlv[2] + v[i][3] * v[j][3] * rlv[3];
    }
    __syncthreads();

    // 5) U_out = Y * S, coalesced store
#pragma unroll
    for (int i = 0; i < 4; ++i) {
        const int cell = t + i * 512;
        const int row = cell >> 5, d = cell & 31;
        const float4 y = *(const float4*)(Yl + row * 132 + 4 * d);
        const float* S = Sm + row * 16;
        float4 o4;
        o4.x = y.x * S[0]  + y.y * S[4]  + y.z * S[8]  + y.w * S[12];
        o4.y = y.x * S[1]  + y.y * S[5]  + y.z * S[9]  + y.w * S[13];
        o4.z = y.x * S[2]  + y.y * S[6]  + y.z * S[10] + y.w * S[14];
        o4.w = y.x * S[3]  + y.y * S[7]  + y.z * S[11] + y.w * S[15];
        *(float4*)(out + ((size_t)(b * N_ + r0 + row)) * COLS + 4 * d) = o4;
    }
}

extern "C" void kernel_launch(void* const* d_in, const int* in_sizes, int n_in,
                              void* d_out, int out_size, void* d_ws, size_t ws_size,
                              hipStream_t stream)
{
    const float* U      = (const float*)d_in[0];
    const float* A      = (const float*)d_in[1];
    const float* Wself  = (const float*)d_in[2];
    const float* Wneigh = (const float*)d_in[3];
    const float* bias   = (const float*)d_in[4];
    float* out = (float*)d_out;

    unsigned short* Btg = (unsigned short*)d_ws;                    // 4MB bf16
    float* Mself = (float*)((char*)d_ws + (size_t)4 * 1024 * 1024); // 8.4MB f32

    mneigh_t_kernel<<<512, 256, 0, stream>>>(U, Wneigh, Wself, Btg, Mself);
    gemm_proj_kernel<<<256, 512, 0, stream>>>(A, Btg, Mself, bias, out);
}

// Round 9
// 49.109 us; speedup vs baseline: 1.1544x; 1.1544x over previous
//
#include <hip/hip_runtime.h>
#include <math.h>

constexpr int B_   = 8;
constexpr int N_   = 2048;
constexpr int D_   = 32;
constexpr int PIN  = 8;
constexpr int POUT = 4;
constexpr int COLS = 128;      // D_*POUT
constexpr int BM   = 32;       // GEMM row tile
constexpr int BK   = 64;       // GEMM k tile
constexpr int NT   = N_ / BK;  // 32 k-steps

using f32x4  = __attribute__((ext_vector_type(4))) float;
using bf16x8 = __attribute__((ext_vector_type(8))) short;

__device__ __forceinline__ unsigned short f2bf(float f) {
    union { float f; unsigned u; } v; v.f = f;
    unsigned u = v.u + 0x7fffu + ((v.u >> 16) & 1u);   // RTNE
    return (unsigned short)(u >> 16);
}

// ---- kernel T: Btg[b][col=4d+o][n] = bf16(U@Wn); Mself[b][n][4d+o] = U@Ws ----
// 1024 blocks x 256 thr (4 blocks/CU). b = bid&7 -> batch panel produced on the
// same XCD whose L2 kernel G (batch = blockIdx&7) will read it from.
__global__ __launch_bounds__(256) void mneigh_t_kernel(
    const float* __restrict__ U, const float* __restrict__ Wn,
    const float* __restrict__ Ws, unsigned short* __restrict__ Btg,
    float* __restrict__ Mself)
{
    const int bt = blockIdx.x;       // 1024 blocks
    const int b  = bt & 7;           // batch == XCD id (aligns with G)
    const int n0 = (bt >> 3) * 16;   // 16 n-rows per block
    const int t  = threadIdx.x;
    const int d  = t >> 3;           // 0..31
    const int ns = t & 7;            // 0..7 -> rows n0+2ns, +1

    float wn[PIN][POUT], ws[PIN][POUT];
#pragma unroll
    for (int p = 0; p < PIN; ++p)
#pragma unroll
        for (int o = 0; o < POUT; ++o) {
            wn[p][o] = Wn[p * POUT + o];
            ws[p][o] = Ws[p * POUT + o];
        }

    union { unsigned short s[2]; unsigned int u; } ob[POUT];
    const float* Ub = U + (((size_t)(b * N_ + n0 + ns * 2)) * D_ + d) * PIN;
#pragma unroll
    for (int ni = 0; ni < 2; ++ni) {
        const float4 u0 = *(const float4*)(Ub + (size_t)ni * D_ * PIN);
        const float4 u1 = *(const float4*)(Ub + (size_t)ni * D_ * PIN + 4);
        const float uu[8] = {u0.x, u0.y, u0.z, u0.w, u1.x, u1.y, u1.z, u1.w};
        float4 ms;
#pragma unroll
        for (int o = 0; o < POUT; ++o) {
            float sn = 0.f, ss = 0.f;
#pragma unroll
            for (int p = 0; p < PIN; ++p) {
                sn = fmaf(uu[p], wn[p][o], sn);
                ss = fmaf(uu[p], ws[p][o], ss);
            }
            ob[o].s[ni] = f2bf(sn);
            ((float*)&ms)[o] = ss;
        }
        *(float4*)(Mself + ((size_t)(b * N_ + n0 + ns * 2 + ni)) * COLS + d * 4) = ms;
    }
#pragma unroll
    for (int o = 0; o < POUT; ++o) {
        unsigned short* dst =
            Btg + ((size_t)(b * COLS + d * 4 + o)) * N_ + n0 + ns * 2;
        *(unsigned int*)dst = ob[o].u;
    }
}

// ---- kernel G: M_agg = A @ Mneigh (bf16 MFMA); Y=relu(+Mself+bias); polar ----
// (verbatim from R5: depth-2 reg pipeline, dbuf LDS, raw barriers, 49.1 us)
__global__ __launch_bounds__(512) void gemm_proj_kernel(
    const float* __restrict__ A, const unsigned short* __restrict__ Btg,
    const float* __restrict__ Mself, const float* __restrict__ bias,
    float* __restrict__ out)
{
    __shared__ unsigned char smem[40960];
    float* Yl = (float*)smem;
    float* Gp = (float*)(smem + 16896);
    float* Sm = (float*)(smem + 22016);

    // T1: bijective XCD swizzle (512 % 8 == 0): batch = blockIdx&7 = XCD id.
    const int bid = (blockIdx.x & 7) * 64 + (blockIdx.x >> 3);
    const int b   = bid >> 6;
    const int r0  = (bid & 63) * BM;
    const int t   = threadIdx.x;
    const int lane = t & 63, wv = t >> 6;
    const int wr = wv >> 2, wc = wv & 3;       // wave -> 16-row x 32-col subtile
    const int q = lane >> 4, rl = lane & 15;
    const unsigned swz = (unsigned)((lane & 7) << 4);
    const int rA = wr * 16 + rl;

    const int arow = t >> 4, af4 = t & 15;               // A: 4 f32/thread
    const unsigned aswz = (unsigned)((arow & 7) << 4);
    const int bcol = t >> 2, bsg = t & 3;                // B: 16 bf16/thread
    const unsigned bswz = (unsigned)((bcol & 7) << 4);

    const float* Ab = A + (size_t)b * N_ * N_ + (size_t)r0 * N_;
    const unsigned short* Bb = Btg + (size_t)b * COLS * N_;
    const float* Mb = Mself + ((size_t)(b * N_ + r0)) * COLS;

    // epilogue Mself prefetch (oldest outstanding loads -> free completion)
    const int cell0 = t, cell1 = t + 512;
    const float4 mpre0 = *(const float4*)(Mb + (size_t)(cell0 >> 5) * COLS + (cell0 & 31) * 4);
    const float4 mpre1 = *(const float4*)(Mb + (size_t)(cell1 >> 5) * COLS + (cell1 & 31) * 4);

    f32x4 acc[2] = {f32x4{0, 0, 0, 0}, f32x4{0, 0, 0, 0}};

    float4 A0, A1; int4 B00, B01, B10, B11;
    A0  = *(const float4*)(Ab + (size_t)arow * N_ + af4 * 4);
    B00 = *(const int4*)(Bb + (size_t)bcol * N_ + bsg * 16);
    B01 = *(const int4*)(Bb + (size_t)bcol * N_ + bsg * 16 + 8);
    A1  = *(const float4*)(Ab + (size_t)arow * N_ + BK + af4 * 4);
    B10 = *(const int4*)(Bb + (size_t)bcol * N_ + BK + bsg * 16);
    B11 = *(const int4*)(Bb + (size_t)bcol * N_ + BK + bsg * 16 + 8);
    {
        union { unsigned short s[4]; int2 v; } pk;
        pk.s[0] = f2bf(A0.x); pk.s[1] = f2bf(A0.y);
        pk.s[2] = f2bf(A0.z); pk.s[3] = f2bf(A0.w);
        *(int2*)(smem + arow * 128 + ((unsigned)(af4 * 8) ^ aswz)) = pk.v;
        *(int4*)(smem + 8192 + bcol * 128 + ((unsigned)(bsg * 32) ^ bswz)) = B00;
        *(int4*)(smem + 8192 + bcol * 128 + ((unsigned)(bsg * 32 + 16) ^ bswz)) = B01;
    }
    asm volatile("s_waitcnt lgkmcnt(0)" ::: "memory");
    __builtin_amdgcn_s_barrier();

#define PIPE_STEP(KT, RA_, RB0_, RB1_, WA_, WB0_, WB1_, CUR)                     \
    {                                                                            \
        const int k2 = ((KT) + 2 < NT) ? ((KT) + 2) * BK : 0;                    \
        RA_  = *(const float4*)(Ab + (size_t)arow * N_ + k2 + af4 * 4);          \
        RB0_ = *(const int4*)(Bb + (size_t)bcol * N_ + k2 + bsg * 16);           \
        RB1_ = *(const int4*)(Bb + (size_t)bcol * N_ + k2 + bsg * 16 + 8);       \
        const unsigned abase = (CUR) * 4096u;                                    \
        const unsigned bbase = 8192u + (CUR) * 16384u;                           \
        __builtin_amdgcn_s_setprio(1);                                           \
        _Pragma("unroll")                                                        \
        for (int ks = 0; ks < 2; ++ks) {                                         \
            const bf16x8 af = *(const bf16x8*)(                                  \
                smem + abase + rA * 128 + ((unsigned)(ks * 64 + q * 16) ^ swz)); \
            _Pragma("unroll")                                                    \
            for (int cf = 0; cf < 2; ++cf) {                                     \
                const int rB = wc * 32 + cf * 16 + rl;                           \
                const bf16x8 bfr = *(const bf16x8*)(                             \
                    smem + bbase + rB * 128 +                                    \
                    ((unsigned)(ks * 64 + q * 16) ^ swz));                       \
                acc[cf] = __builtin_amdgcn_mfma_f32_16x16x32_bf16(               \
                    af, bfr, acc[cf], 0, 0, 0);                                  \
            }                                                                    \
        }                                                                        \
        __builtin_amdgcn_s_setprio(0);                                           \
        {                                                                        \
            union { unsigned short s[4]; int2 v; } pk;                           \
            pk.s[0] = f2bf(WA_.x); pk.s[1] = f2bf(WA_.y);                        \
            pk.s[2] = f2bf(WA_.z); pk.s[3] = f2bf(WA_.w);                        \
            const unsigned nab = ((CUR) ^ 1u) * 4096u;                           \
            const unsigned nbb = 8192u + ((CUR) ^ 1u) * 16384u;                  \
            *(int2*)(smem + nab + arow * 128 +                                   \
                     ((unsigned)(af4 * 8) ^ aswz)) = pk.v;                       \
            *(int4*)(smem + nbb + bcol * 128 +                                   \
                     ((unsigned)(bsg * 32) ^ bswz)) = WB0_;                      \
            *(int4*)(smem + nbb + bcol * 128 +                                   \
                     ((unsigned)(bsg * 32 + 16) ^ bswz)) = WB1_;                 \
        }                                                                        \
        asm volatile("s_waitcnt lgkmcnt(0)" ::: "memory");                       \
        __builtin_amdgcn_s_barrier();                                            \
    }

    for (int kt = 0; kt < NT; kt += 2) {
        PIPE_STEP(kt,     A0, B00, B01, A1, B10, B11, 0u)
        PIPE_STEP(kt + 1, A1, B10, B11, A0, B00, B01, 1u)
    }
#undef PIPE_STEP
    __syncthreads();   // full drain once; smem repurposed below

    // ---- epilogue ----
#pragma unroll
    for (int cf = 0; cf < 2; ++cf)
#pragma unroll
        for (int r = 0; r < 4; ++r) {
            const int row = wr * 16 + q * 4 + r;
            const int col = wc * 32 + cf * 16 + rl;
            Yl[row * 132 + col] = acc[cf][r];
        }
    __syncthreads();

    const float bz[4] = {bias[0], bias[1], bias[2], bias[3]};
#pragma unroll
    for (int i = 0; i < 2; ++i) {
        const int cell = t + i * 512;     // 1024 cells = 32 rows x 32 d
        const int row = cell >> 5, d = cell & 31;
        const float4 m = (i == 0) ? mpre0 : mpre1;
        const int idx = row * 132 + d * 4;
        float4 y = *(const float4*)(Yl + idx);
        y.x = fmaxf(y.x + m.x + bz[0], 0.f);
        y.y = fmaxf(y.y + m.y + bz[1], 0.f);
        y.z = fmaxf(y.z + m.z + bz[2], 0.f);
        y.w = fmaxf(y.w + m.w + bz[3], 0.f);
        *(float4*)(Yl + idx) = y;
    }
    __syncthreads();

    if (t < 128) {
        const int row = t >> 2, qd = t & 3;
        float g[10] = {0,0,0,0,0,0,0,0,0,0};
#pragma unroll
        for (int d = qd * 8; d < qd * 8 + 8; ++d) {
            const float4 y = *(const float4*)(Yl + row * 132 + 4 * d);
            g[0] = fmaf(y.x, y.x, g[0]); g[1] = fmaf(y.x, y.y, g[1]);
            g[2] = fmaf(y.x, y.z, g[2]); g[3] = fmaf(y.x, y.w, g[3]);
            g[4] = fmaf(y.y, y.y, g[4]); g[5] = fmaf(y.y, y.z, g[5]);
            g[6] = fmaf(y.y, y.w, g[6]); g[7] = fmaf(y.z, y.z, g[7]);
            g[8] = fmaf(y.z, y.w, g[8]); g[9] = fmaf(y.w, y.w, g[9]);
        }
        float* gp = Gp + (row * 4 + qd) * 10;
#pragma unroll
        for (int k = 0; k < 10; ++k) gp[k] = g[k];
    }
    __syncthreads();

    if (t < 32) {
        float gg[10];
#pragma unroll
        for (int k = 0; k < 10; ++k)
            gg[k] = Gp[(t * 4 + 0) * 10 + k] + Gp[(t * 4 + 1) * 10 + k] +
                    Gp[(t * 4 + 2) * 10 + k] + Gp[(t * 4 + 3) * 10 + k];
        float m[4][4] = {{gg[0], gg[1], gg[2], gg[3]},
                         {gg[1], gg[4], gg[5], gg[6]},
                         {gg[2], gg[5], gg[7], gg[8]},
                         {gg[3], gg[6], gg[8], gg[9]}};
        float v[4][4] = {{1,0,0,0},{0,1,0,0},{0,0,1,0},{0,0,0,1}};
        for (int sweep = 0; sweep < 6; ++sweep) {
#pragma unroll
            for (int p = 0; p < 3; ++p) {
#pragma unroll
                for (int qq = p + 1; qq < 4; ++qq) {
                    const float apq = m[p][qq];
                    if (fabsf(apq) < 1e-28f) continue;
                    const float theta = (m[qq][qq] - m[p][p]) / (2.f * apq);
                    const float tt = copysignf(1.f, theta) /
                        (fabsf(theta) + sqrtf(fmaf(theta, theta, 1.f)));
                    const float c = 1.f / sqrtf(fmaf(tt, tt, 1.f));
                    const float s = tt * c;
#pragma unroll
                    for (int k = 0; k < 4; ++k) {
                        const float mkp = m[k][p], mkq = m[k][qq];
                        m[k][p] = c * mkp - s * mkq;
                        m[k][qq] = s * mkp + c * mkq;
                    }
#pragma unroll
                    for (int k = 0; k < 4; ++k) {
                        const float mpk = m[p][k], mqk = m[qq][k];
                        m[p][k] = c * mpk - s * mqk;
                        m[qq][k] = s * mpk + c * mqk;
                    }
#pragma unroll
                    for (int k = 0; k < 4; ++k) {
                        const float vkp = v[k][p], vkq = v[k][qq];
                        v[k][p] = c * vkp - s * vkq;
                        v[k][qq] = s * vkp + c * vkq;
                    }
                }
            }
        }
        const float lam[4] = {m[0][0], m[1][1], m[2][2], m[3][3]};
        const float lmax = fmaxf(fmaxf(lam[0], lam[1]), fmaxf(lam[2], lam[3]));
        const float lfloor = fmaxf(lmax * 1e-12f, 1e-30f);
        float rlv[4];
#pragma unroll
        for (int k = 0; k < 4; ++k) rlv[k] = 1.f / sqrtf(fmaxf(lam[k], lfloor));
#pragma unroll
        for (int i = 0; i < 4; ++i)
#pragma unroll
            for (int j = 0; j < 4; ++j)
                Sm[t * 16 + i * 4 + j] =
                    v[i][0] * v[j][0] * rlv[0] + v[i][1] * v[j][1] * rlv[1] +
                    v[i][2] * v[j][2] * rlv[2] + v[i][3] * v[j][3] * rlv[3];
    }
    __syncthreads();

#pragma unroll
    for (int i = 0; i < 2; ++i) {
        const int cell = t + i * 512;
        const int row = cell >> 5, d = cell & 31;
        const float4 y = *(const float4*)(Yl + row * 132 + 4 * d);
        const float* S = Sm + row * 16;
        float4 o4;
        o4.x = y.x * S[0]  + y.y * S[4]  + y.z * S[8]  + y.w * S[12];
        o4.y = y.x * S[1]  + y.y * S[5]  + y.z * S[9]  + y.w * S[13];
        o4.z = y.x * S[2]  + y.y * S[6]  + y.z * S[10] + y.w * S[14];
        o4.w = y.x * S[3]  + y.y * S[7]  + y.z * S[11] + y.w * S[15];
        *(float4*)(out + ((size_t)(b * N_ + r0 + row)) * COLS + 4 * d) = o4;
    }
}

extern "C" void kernel_launch(void* const* d_in, const int* in_sizes, int n_in,
                              void* d_out, int out_size, void* d_ws, size_t ws_size,
                              hipStream_t stream)
{
    const float* U      = (const float*)d_in[0];
    const float* A      = (const float*)d_in[1];
    const float* Wself  = (const float*)d_in[2];
    const float* Wneigh = (const float*)d_in[3];
    const float* bias   = (const float*)d_in[4];
    float* out = (float*)d_out;

    unsigned short* Btg = (unsigned short*)d_ws;                    // 4MB bf16
    float* Mself = (float*)((char*)d_ws + (size_t)4 * 1024 * 1024); // 8.4MB f32

    mneigh_t_kernel<<<1024, 256, 0, stream>>>(U, Wneigh, Wself, Btg, Mself);
    gemm_proj_kernel<<<512, 512, 0, stream>>>(A, Btg, Mself, bias, out);
}

// Round 11
// 48.453 us; speedup vs baseline: 1.1701x; 1.0135x over previous
//
#include <hip/hip_runtime.h>
#include <math.h>

constexpr int B_   = 8;
constexpr int N_   = 2048;
constexpr int D_   = 32;
constexpr int PIN  = 8;
constexpr int POUT = 4;
constexpr int COLS = 128;      // D_*POUT
constexpr int BM   = 32;       // GEMM row tile
constexpr int BK   = 64;       // GEMM k tile
constexpr int NT   = N_ / BK;  // 32 k-steps

using f32x4  = __attribute__((ext_vector_type(4))) float;
using bf16x8 = __attribute__((ext_vector_type(8))) short;

__device__ __forceinline__ unsigned short f2bf(float f) {
    union { float f; unsigned u; } v; v.f = f;
    unsigned u = v.u + 0x7fffu + ((v.u >> 16) & 1u);   // RTNE
    return (unsigned short)(u >> 16);
}

// ---- kernel T: Bt[b][col=4d+o][n] = bf16( sum_p U[b][n][d][p] * Wn[p][o] ) ----
__global__ __launch_bounds__(256) void mneigh_t_kernel(
    const float* __restrict__ U, const float* __restrict__ Wn,
    unsigned short* __restrict__ Btg)
{
    const int bt = blockIdx.x;
    const int b  = bt >> 5;
    const int n0 = (bt & 31) * 64;
    const int t  = threadIdx.x;
    const int d  = t >> 3;       // 0..31
    const int ns = t & 7;        // n-segment of 8

    float w[PIN][POUT];
#pragma unroll
    for (int p = 0; p < PIN; ++p)
#pragma unroll
        for (int o = 0; o < POUT; ++o) w[p][o] = Wn[p * POUT + o];

    union { unsigned short s[8]; int4 v; } ob[POUT];
    const float* Ub = U + (((size_t)(b * N_ + n0 + ns * 8)) * D_ + d) * PIN;
#pragma unroll
    for (int ni = 0; ni < 8; ++ni) {
        const float4 u0 = *(const float4*)(Ub + (size_t)ni * D_ * PIN);
        const float4 u1 = *(const float4*)(Ub + (size_t)ni * D_ * PIN + 4);
        const float uu[8] = {u0.x, u0.y, u0.z, u0.w, u1.x, u1.y, u1.z, u1.w};
#pragma unroll
        for (int o = 0; o < POUT; ++o) {
            float s = 0.f;
#pragma unroll
            for (int p = 0; p < PIN; ++p) s = fmaf(uu[p], w[p][o], s);
            ob[o].s[ni] = f2bf(s);
        }
    }
#pragma unroll
    for (int o = 0; o < POUT; ++o) {
        unsigned short* dst =
            Btg + ((size_t)(b * COLS + d * 4 + o)) * N_ + n0 + ns * 8;
        *(int4*)dst = ob[o].v;
    }
}

// ---- kernel G: M_agg = A @ Mneigh (bf16 MFMA); Y=relu(+Mself+bias); polar ----
// grid 512 blocks (2/CU), 512 thr, double-buffered LDS, 1 barrier per k-tile.
__global__ __launch_bounds__(512) void gemm_proj_kernel(
    const float* __restrict__ A, const unsigned short* __restrict__ Btg,
    const float* __restrict__ U, const float* __restrict__ Wsg,
    const float* __restrict__ bias, float* __restrict__ out)
{
    __shared__ unsigned char smem[40960];
    // staging: Abuf[2] bf16 [32][64] swz @0 (2x4KB); Bbuf[2] bf16 [128][64] swz @8192
    // epilogue reuse: Yl f32 [32][132] @0 (16896); Gp [32][4][10] @16896; Sm @22016
    float* Yl = (float*)smem;
    float* Gp = (float*)(smem + 16896);
    float* Sm = (float*)(smem + 22016);

    // T1: bijective XCD swizzle (512 % 8 == 0). XCD x owns batch x -> its 4MB
    // B-panel fits the per-XCD L2.
    const int bid = (blockIdx.x & 7) * 64 + (blockIdx.x >> 3);
    const int b   = bid >> 6;
    const int r0  = (bid & 63) * BM;
    const int t   = threadIdx.x;
    const int lane = t & 63, wv = t >> 6;
    const int wr = wv >> 2, wc = wv & 3;       // wave -> 16-row x 32-col subtile
    const int q = lane >> 4, rl = lane & 15;
    const unsigned swz = (unsigned)((lane & 7) << 4);
    const int rA = wr * 16 + rl;

    // staging decomposition (512 threads)
    const int arow = t >> 4, af4 = t & 15;               // A: 4 f32/thread
    const unsigned aswz = (unsigned)((arow & 7) << 4);
    const int bcol = t >> 2, bsg = t & 3;                // B: 16 bf16/thread
    const unsigned bswz = (unsigned)((bcol & 7) << 4);

    const float* Ab = A + (size_t)b * N_ * N_ + (size_t)r0 * N_;
    const unsigned short* Bb = Btg + (size_t)b * COLS * N_;

    f32x4 acc[2] = {f32x4{0, 0, 0, 0}, f32x4{0, 0, 0, 0}};

    // ---- prologue: stage k-tile 0 into buf0 ----
    {
        const float4 a0 = *(const float4*)(Ab + (size_t)arow * N_ + af4 * 4);
        const int4 b0 = *(const int4*)(Bb + (size_t)bcol * N_ + bsg * 16);
        const int4 b1 = *(const int4*)(Bb + (size_t)bcol * N_ + bsg * 16 + 8);
        union { unsigned short s[4]; int2 v; } pk;
        pk.s[0] = f2bf(a0.x); pk.s[1] = f2bf(a0.y);
        pk.s[2] = f2bf(a0.z); pk.s[3] = f2bf(a0.w);
        *(int2*)(smem + arow * 128 + ((unsigned)(af4 * 8) ^ aswz)) = pk.v;
        *(int4*)(smem + 8192 + bcol * 128 + ((unsigned)(bsg * 32) ^ bswz)) = b0;
        *(int4*)(smem + 8192 + bcol * 128 + ((unsigned)(bsg * 32 + 16) ^ bswz)) = b1;
    }
    __syncthreads();

    for (int kt = 0; kt < NT; ++kt) {
        const unsigned cur = (unsigned)(kt & 1);
        const unsigned nxt = cur ^ 1u;
        float4 na0; int4 nb0, nb1;
        const bool more = (kt + 1 < NT);
        if (more) {   // T14: issue next-tile loads before compute
            const int k0 = (kt + 1) * BK;
            na0 = *(const float4*)(Ab + (size_t)arow * N_ + k0 + af4 * 4);
            nb0 = *(const int4*)(Bb + (size_t)bcol * N_ + k0 + bsg * 16);
            nb1 = *(const int4*)(Bb + (size_t)bcol * N_ + k0 + bsg * 16 + 8);
        }
        const unsigned abase = cur * 4096u;
        const unsigned bbase = 8192u + cur * 16384u;
        __builtin_amdgcn_s_setprio(1);
#pragma unroll
        for (int ks = 0; ks < 2; ++ks) {
            const bf16x8 af = *(const bf16x8*)(
                smem + abase + rA * 128 + ((unsigned)(ks * 64 + q * 16) ^ swz));
#pragma unroll
            for (int cf = 0; cf < 2; ++cf) {
                const int rB = wc * 32 + cf * 16 + rl;
                const bf16x8 bfr = *(const bf16x8*)(
                    smem + bbase + rB * 128 + ((unsigned)(ks * 64 + q * 16) ^ swz));
                acc[cf] = __builtin_amdgcn_mfma_f32_16x16x32_bf16(af, bfr, acc[cf],
                                                                  0, 0, 0);
            }
        }
        __builtin_amdgcn_s_setprio(0);
        if (more) {   // pack into the other buffer (no race with current reads)
            union { unsigned short s[4]; int2 v; } pk;
            pk.s[0] = f2bf(na0.x); pk.s[1] = f2bf(na0.y);
            pk.s[2] = f2bf(na0.z); pk.s[3] = f2bf(na0.w);
            *(int2*)(smem + nxt * 4096u + arow * 128 +
                     ((unsigned)(af4 * 8) ^ aswz)) = pk.v;
            *(int4*)(smem + 8192u + nxt * 16384u + bcol * 128 +
                     ((unsigned)(bsg * 32) ^ bswz)) = nb0;
            *(int4*)(smem + 8192u + nxt * 16384u + bcol * 128 +
                     ((unsigned)(bsg * 32 + 16) ^ bswz)) = nb1;
        }
        __syncthreads();
    }

    // ---- epilogue ----
    // 1) M_agg -> Yl   (C/D map: col=lane&15, row=(lane>>4)*4+r  [m89])
#pragma unroll
    for (int cf = 0; cf < 2; ++cf)
#pragma unroll
        for (int r = 0; r < 4; ++r) {
            const int row = wr * 16 + q * 4 + r;
            const int col = wc * 32 + cf * 16 + rl;
            Yl[row * 132 + col] = acc[cf][r];
        }
    __syncthreads();

    // 2) Y = relu(M_agg + M_self + bias), M_self recomputed from U
    float ws[PIN][POUT];
#pragma unroll
    for (int p = 0; p < PIN; ++p)
#pragma unroll
        for (int o = 0; o < POUT; ++o) ws[p][o] = Wsg[p * POUT + o];
    const float bz[4] = {bias[0], bias[1], bias[2], bias[3]};
#pragma unroll
    for (int i = 0; i < 2; ++i) {
        const int cell = t + i * 512;     // 1024 cells = 32 rows x 32 d
        const int row = cell >> 5, d = cell & 31;
        const float* up = U + (((size_t)(b * N_ + r0 + row)) * D_ + d) * PIN;
        const float4 u0 = *(const float4*)up;
        const float4 u1 = *(const float4*)(up + 4);
        const float uu[8] = {u0.x, u0.y, u0.z, u0.w, u1.x, u1.y, u1.z, u1.w};
#pragma unroll
        for (int o = 0; o < POUT; ++o) {
            float s = bz[o];
#pragma unroll
            for (int p = 0; p < PIN; ++p) s = fmaf(uu[p], ws[p][o], s);
            const int idx = row * 132 + d * 4 + o;
            Yl[idx] = fmaxf(Yl[idx] + s, 0.f);
        }
    }
    __syncthreads();

    // 3) G partials: 4 threads per row
    if (t < 128) {
        const int row = t >> 2, qd = t & 3;
        float g[10] = {0,0,0,0,0,0,0,0,0,0};
#pragma unroll
        for (int d = qd * 8; d < qd * 8 + 8; ++d) {
            const float4 y = *(const float4*)(Yl + row * 132 + 4 * d);
            g[0] = fmaf(y.x, y.x, g[0]); g[1] = fmaf(y.x, y.y, g[1]);
            g[2] = fmaf(y.x, y.z, g[2]); g[3] = fmaf(y.x, y.w, g[3]);
            g[4] = fmaf(y.y, y.y, g[4]); g[5] = fmaf(y.y, y.z, g[5]);
            g[6] = fmaf(y.y, y.w, g[6]); g[7] = fmaf(y.z, y.z, g[7]);
            g[8] = fmaf(y.z, y.w, g[8]); g[9] = fmaf(y.w, y.w, g[9]);
        }
        float* gp = Gp + (row * 4 + qd) * 10;
#pragma unroll
        for (int k = 0; k < 10; ++k) gp[k] = g[k];
    }
    __syncthreads();

    // 4) Jacobi eigendecomposition + S = V diag(1/sqrt(l)) V^T  (1 thread/row)
    if (t < 32) {
        float gg[10];
#pragma unroll
        for (int k = 0; k < 10; ++k)
            gg[k] = Gp[(t * 4 + 0) * 10 + k] + Gp[(t * 4 + 1) * 10 + k] +
                    Gp[(t * 4 + 2) * 10 + k] + Gp[(t * 4 + 3) * 10 + k];
        float m[4][4] = {{gg[0], gg[1], gg[2], gg[3]},
                         {gg[1], gg[4], gg[5], gg[6]},
                         {gg[2], gg[5], gg[7], gg[8]},
                         {gg[3], gg[6], gg[8], gg[9]}};
        float v[4][4] = {{1,0,0,0},{0,1,0,0},{0,0,1,0},{0,0,0,1}};
        for (int sweep = 0; sweep < 6; ++sweep) {
#pragma unroll
            for (int p = 0; p < 3; ++p) {
#pragma unroll
                for (int qq = p + 1; qq < 4; ++qq) {
                    const float apq = m[p][qq];
                    if (fabsf(apq) < 1e-28f) continue;
                    const float theta = (m[qq][qq] - m[p][p]) / (2.f * apq);
                    const float tt = copysignf(1.f, theta) /
                        (fabsf(theta) + sqrtf(fmaf(theta, theta, 1.f)));
                    const float c = 1.f / sqrtf(fmaf(tt, tt, 1.f));
                    const float s = tt * c;
#pragma unroll
                    for (int k = 0; k < 4; ++k) {
                        const float mkp = m[k][p], mkq = m[k][qq];
                        m[k][p] = c * mkp - s * mkq;
                        m[k][qq] = s * mkp + c * mkq;
                    }
#pragma unroll
                    for (int k = 0; k < 4; ++k) {
                        const float mpk = m[p][k], mqk = m[qq][k];
                        m[p][k] = c * mpk - s * mqk;
                        m[qq][k] = s * mpk + c * mqk;
                    }
#pragma unroll
                    for (int k = 0; k < 4; ++k) {
                        const float vkp = v[k][p], vkq = v[k][qq];
                        v[k][p] = c * vkp - s * vkq;
                        v[k][qq] = s * vkp + c * vkq;
                    }
                }
            }
        }
        const float lam[4] = {m[0][0], m[1][1], m[2][2], m[3][3]};
        const float lmax = fmaxf(fmaxf(lam[0], lam[1]), fmaxf(lam[2], lam[3]));
        const float lfloor = fmaxf(lmax * 1e-12f, 1e-30f);
        float rlv[4];
#pragma unroll
        for (int k = 0; k < 4; ++k) rlv[k] = 1.f / sqrtf(fmaxf(lam[k], lfloor));
#pragma unroll
        for (int i = 0; i < 4; ++i)
#pragma unroll
            for (int j = 0; j < 4; ++j)
                Sm[t * 16 + i * 4 + j] =
                    v[i][0] * v[j][0] * rlv[0] + v[i][1] * v[j][1] * rlv[1] +
                    v[i][2] * v[j][2] * rlv[2] + v[i][3] * v[j][3] * rlv[3];
    }
    __syncthreads();

    // 5) U_out = Y * S, coalesced store
#pragma unroll
    for (int i = 0; i < 2; ++i) {
        const int cell = t + i * 512;
        const int row = cell >> 5, d = cell & 31;
        const float4 y = *(const float4*)(Yl + row * 132 + 4 * d);
        const float* S = Sm + row * 16;
        float4 o4;
        o4.x = y.x * S[0]  + y.y * S[4]  + y.z * S[8]  + y.w * S[12];
        o4.y = y.x * S[1]  + y.y * S[5]  + y.z * S[9]  + y.w * S[13];
        o4.z = y.x * S[2]  + y.y * S[6]  + y.z * S[10] + y.w * S[14];
        o4.w = y.x * S[3]  + y.y * S[7]  + y.z * S[11] + y.w * S[15];
        *(float4*)(out + ((size_t)(b * N_ + r0 + row)) * COLS + 4 * d) = o4;
    }
}

extern "C" void kernel_launch(void* const* d_in, const int* in_sizes, int n_in,
                              void* d_out, int out_size, void* d_ws, size_t ws_size,
                              hipStream_t stream)
{
    const float* U      = (const float*)d_in[0];
    const float* A      = (const float*)d_in[1];
    const float* Wself  = (const float*)d_in[2];
    const float* Wneigh = (const float*)d_in[3];
    const float* bias   = (const float*)d_in[4];
    float* out = (float*)d_out;

    unsigned short* Btg = (unsigned short*)d_ws;   // [8][128][2048] bf16 = 4MB

    mneigh_t_kernel<<<B_ * (N_ / 64), 256, 0, stream>>>(U, Wneigh, Btg);
    gemm_proj_kernel<<<B_ * (N_ / BM), 512, 0, stream>>>(A, Btg, U, Wself, bias,
                                                         out);
}